// Round 4
// baseline (265.348 us; speedup 1.0000x reference)
//
#include <hip/hip_runtime.h>
#include <math.h>

// Problem constants: B=8, Cin=Cout=256, H=W=128, K=3, GROUPS=128 (2 ch/group)
#define BATCH 8
#define CH    256
#define HH    128
#define WW    128
#define HW    (HH*WW)          // 16384
#define NGRP  128
#define EPS   1e-7f

// ---------------- Kernel 1: per-(b,c) mean / rstd ----------------
__global__ __launch_bounds__(256) void stats_kernel(
    const float* __restrict__ x, float* __restrict__ mean_o, float* __restrict__ rstd_o)
{
    const int c = blockIdx.x;                       // 0..2047 = b*256+c
    const float4* p = (const float4*)(x + (size_t)c * HW);
    float s = 0.f, ss = 0.f;
    #pragma unroll 4
    for (int i = threadIdx.x; i < HW/4; i += 256) {
        float4 v = p[i];
        s  += v.x + v.y + v.z + v.w;
        ss += v.x*v.x + v.y*v.y + v.z*v.z + v.w*v.w;
    }
    #pragma unroll
    for (int off = 32; off > 0; off >>= 1) {
        s  += __shfl_down(s,  off);
        ss += __shfl_down(ss, off);
    }
    __shared__ float ls[4], lss[4];
    const int wave = threadIdx.x >> 6;
    if ((threadIdx.x & 63) == 0) { ls[wave] = s; lss[wave] = ss; }
    __syncthreads();
    if (threadIdx.x == 0) {
        s  = ls[0]  + ls[1]  + ls[2]  + ls[3];
        ss = lss[0] + lss[1] + lss[2] + lss[3];
        const float m = s * (1.0f / (float)HW);
        float var = (ss - s * m) * (1.0f / (float)(HW - 1));   // Bessel (N-1)
        var = fmaxf(var, 0.0f);
        mean_o[c] = m;
        rstd_o[c] = 1.0f / (sqrtf(var) + EPS);                 // 1/(std+eps)
    }
}

// ---------------- Kernel 2: normalize-folded grouped 3x3 (+1x1) + bias ----------
// Tile: 32 rows x 128 cols (full width). LDS = 2ch x 34 x 136 floats = 37 KB
// -> 4 blocks/CU resident; 4096 blocks total = 16/CU pipelined so staging of
// the next block overlaps conv of the current.
// Image col gw <-> xs float col gw+4 (gw=-1 -> 3, gw=128 -> 132).
// Halo cells hold the channel mean m: (m - m)*rstd = 0 == reference zero-pad
// of the NORMALIZED input, with normalization folded into weights/bias.
#define TH  32
#define XSS 136    // row stride in floats (544 B, 16B-aligned); cols 132/133 = right halo

__global__ __launch_bounds__(256, 4) void conv_kernel(
    const float* __restrict__ x,      // [8,256,128,128]
    const float* __restrict__ dwk,    // [8,256,2,3,3]
    const float* __restrict__ pwk,    // [8,256,2]
    const float* __restrict__ bias,   // [8,256]
    const float* __restrict__ mean_i, // [2048]
    const float* __restrict__ rstd_i, // [2048]
    float* __restrict__ out)          // [8,256,128,128]
{
    const int gh0 = blockIdx.x * TH;      // first output row of tile
    const int g   = blockIdx.y;
    const int b   = blockIdx.z;
    const int bc0 = b * CH + g * 2;
    const int tid = threadIdx.x;

    __shared__ float xs[2][TH + 2][XSS];  // 36,992 B

    const float m0 = mean_i[bc0],     r0 = rstd_i[bc0];
    const float m1 = mean_i[bc0 + 1], r1 = rstd_i[bc0 + 1];
    const float* xb = x + (size_t)bc0 * HW;

    // ---- stage raw x rows gh0-1 .. gh0+32 (halo rows/cells = channel mean) ----
    for (int e = tid; e < 2 * (TH + 2) * 32; e += 256) {   // 2176 float4
        const int ci  = e / ((TH + 2) * 32);
        const int rem = e - ci * ((TH + 2) * 32);
        const int row = rem >> 5;
        const int c4  = rem & 31;
        const int gh  = gh0 + row - 1;
        const float mv = ci ? m1 : m0;
        float4 v = make_float4(mv, mv, mv, mv);
        if (gh >= 0 && gh < HH)
            v = *(const float4*)(xb + (size_t)ci * HW + gh * WW + (c4 << 2));
        *(float4*)&xs[ci][row][4 + (c4 << 2)] = v;
    }
    // left/right halo columns (image cols -1 and 128)
    if (tid < 2 * (TH + 2)) {             // 68 threads
        const int ci  = tid / (TH + 2);
        const int row = tid - ci * (TH + 2);
        const float mv = ci ? m1 : m0;
        xs[ci][row][3]   = mv;
        xs[ci][row][132] = mv;
        xs[ci][row][133] = mv;
    }

    // ---- fold pointwise + rstd into 3x3 weights; fold mean into bias ----
    const float p00 = pwk[(size_t)bc0 * 2 + 0];
    const float p01 = pwk[(size_t)bc0 * 2 + 1];
    const float p10 = pwk[(size_t)bc0 * 2 + 2];
    const float p11 = pwk[(size_t)bc0 * 2 + 3];
    const float* dwb = dwk + (size_t)bc0 * 18;   // [outch][cin][9]
    float we[2][2][9];
    float bb[2] = { bias[bc0], bias[bc0 + 1] };
    #pragma unroll
    for (int cin = 0; cin < 2; ++cin) {
        const float rr = cin ? r1 : r0;
        const float mm = cin ? m1 : m0;
        #pragma unroll
        for (int k = 0; k < 9; ++k) {
            const float w0 = dwb[cin * 9 + k];        // depthwise out-ch 0
            const float w1 = dwb[18 + cin * 9 + k];   // depthwise out-ch 1
            const float e0 = fmaf(p00, w0, p01 * w1) * rr;
            const float e1 = fmaf(p10, w0, p11 * w1) * rr;
            we[0][cin][k] = e0;
            we[1][cin][k] = e1;
            bb[0] -= mm * e0;
            bb[1] -= mm * e1;
        }
    }
    __syncthreads();

    // ---- conv: thread -> 4 cols x 4 rows x 2 out-ch ----
    const int c0 = (tid & 31) << 2;       // output cols c0..c0+3
    const int rb = (tid >> 5) << 2;       // tile-local output rows rb..rb+3

    float acc[4][2][4];                   // [row j][outch][col q]
    #pragma unroll
    for (int j = 0; j < 4; ++j)
        #pragma unroll
        for (int q = 0; q < 4; ++q) { acc[j][0][q] = bb[0]; acc[j][1][q] = bb[1]; }

    #pragma unroll
    for (int xr = 0; xr < 6; ++xr) {      // xs rows rb..rb+5
        #pragma unroll
        for (int cin = 0; cin < 2; ++cin) {
            const float* rowp = &xs[cin][rb + xr][0];
            const float2 L = *(const float2*)(rowp + c0 + 2);  // img cols c0-2,c0-1
            const float4 M = *(const float4*)(rowp + c0 + 4);  // img cols c0..c0+3
            const float2 R = *(const float2*)(rowp + c0 + 8);  // img cols c0+4,c0+5
            const float xv[6] = { L.y, M.x, M.y, M.z, M.w, R.x };
            #pragma unroll
            for (int j = 0; j < 4; ++j) {
                const int ky = xr - j;    // tap row (0..2 valid)
                if (ky < 0 || ky > 2) continue;
                #pragma unroll
                for (int ch = 0; ch < 2; ++ch)
                    #pragma unroll
                    for (int q = 0; q < 4; ++q)
                        #pragma unroll
                        for (int kx = 0; kx < 3; ++kx)
                            acc[j][ch][q] = fmaf(we[ch][cin][ky * 3 + kx],
                                                 xv[q + kx], acc[j][ch][q]);
            }
        }
    }

    float* outb = out + (size_t)bc0 * HW;
    #pragma unroll
    for (int j = 0; j < 4; ++j) {
        const int gr = gh0 + rb + j;
        #pragma unroll
        for (int ch = 0; ch < 2; ++ch) {
            const float4 vv = make_float4(acc[j][ch][0], acc[j][ch][1],
                                          acc[j][ch][2], acc[j][ch][3]);
            *(float4*)(outb + (size_t)ch * HW + gr * WW + c0) = vv;
        }
    }
}

extern "C" void kernel_launch(void* const* d_in, const int* in_sizes, int n_in,
                              void* d_out, int out_size, void* d_ws, size_t ws_size,
                              hipStream_t stream)
{
    const float* x    = (const float*)d_in[0];   // [8,256,128,128]
    const float* dwk  = (const float*)d_in[1];   // [8,256,2,3,3]
    const float* pwk  = (const float*)d_in[2];   // [8,256,2,1,1]
    const float* bias = (const float*)d_in[3];   // [8,256]
    float* out = (float*)d_out;                  // [8,256,128,128]

    float* mean_b = (float*)d_ws;                // 2048 floats
    float* rstd_b = mean_b + BATCH * CH;         // 2048 floats

    stats_kernel<<<BATCH * CH, 256, 0, stream>>>(x, mean_b, rstd_b);

    dim3 grid(HH / TH, NGRP, BATCH);             // (4, 128, 8) = 4096 blocks
    conv_kernel<<<grid, 256, 0, stream>>>(x, dwk, pwk, bias, mean_b, rstd_b, out);
}